// Round 1
// 4925.282 us; speedup vs baseline: 2.0896x; 2.0896x over previous
//
#include <hip/hip_runtime.h>
#include <hip/hip_bf16.h>
#include <math.h>

typedef __attribute__((ext_vector_type(8))) short           short8;   // 8 bf16 (4 VGPRs)
typedef __attribute__((ext_vector_type(8))) unsigned short  ushort8;
typedef __attribute__((ext_vector_type(4))) float           f32x4;

__device__ __forceinline__ float lreluf(float v){ return v >= 0.f ? v : 0.01f*v; }
__device__ __forceinline__ float sigf(float v){ return 1.f/(1.f + expf(-v)); }

#define OP_NONE  0
#define OP_LRELU 1
#define OP_RELU  2

__device__ __forceinline__ float applyOp(float v, int op){
  if (op == OP_LRELU) return v >= 0.f ? v : 0.01f*v;
  if (op == OP_RELU)  return v > 0.f ? v : 0.f;
  return v;
}

// f32 -> bf16 RNE, raw ushort
__device__ __forceinline__ unsigned short f2b(float f){
  unsigned x = __float_as_uint(f);
  unsigned lsb = (x >> 16) & 1u;
  return (unsigned short)((x + 0x7fffu + lsb) >> 16);
}
__device__ __forceinline__ float b2f(unsigned short h){
  return __uint_as_float((unsigned)h << 16);
}

__device__ __forceinline__ float blkSum(float v, float* red){
  int t = threadIdx.x;
  red[t] = v; __syncthreads();
  for (int s = 128; s > 0; s >>= 1){ if (t < s) red[t] += red[t+s]; __syncthreads(); }
  float r = red[0]; __syncthreads();
  return r;
}
__device__ __forceinline__ float blkMax(float v, float* red){
  int t = threadIdx.x;
  red[t] = v; __syncthreads();
  for (int s = 128; s > 0; s >>= 1){ if (t < s) red[t] = fmaxf(red[t], red[t+s]); __syncthreads(); }
  float r = red[0]; __syncthreads();
  return r;
}

// ---- stage 64x32 f32 tile -> split bf16 hi/lo LDS [64][32]. 256 threads. ----
__device__ __forceinline__ void stage2(const float* __restrict__ src, int lda,
    int row0, int rowmax, int k0, int K,
    unsigned short* __restrict__ ldsH, unsigned short* __restrict__ ldsL, int tid)
{
  int r = tid >> 2, kc = (tid & 3) * 8;
  int gr = row0 + r, gk = k0 + kc;
  const float* p = src + (size_t)gr*lda + gk;
  float f[8];
  if (gr < rowmax && gk + 8 <= K && ((lda & 3) == 0)){
    float4 f0 = *(const float4*)p;
    float4 f1 = *(const float4*)(p+4);
    f[0]=f0.x; f[1]=f0.y; f[2]=f0.z; f[3]=f0.w;
    f[4]=f1.x; f[5]=f1.y; f[6]=f1.z; f[7]=f1.w;
  } else {
    #pragma unroll
    for (int j = 0; j < 8; ++j) f[j] = (gr < rowmax && gk + j < K) ? p[j] : 0.f;
  }
  ushort8 vh, vl;
  #pragma unroll
  for (int j = 0; j < 8; ++j){
    unsigned short h = f2b(f[j]);
    vh[j] = h;
    vl[j] = f2b(f[j] - b2f(h));
  }
  *(ushort8*)&ldsH[r*32 + kc] = vh;
  *(ushort8*)&ldsL[r*32 + kc] = vl;
}

// 3-product split-precision accumulate: acc += (aH+aL)*(bH+bL) (drop lo*lo)
__device__ __forceinline__ f32x4 mfma3(short8 aH, short8 aL, short8 bH, short8 bL, f32x4 acc){
  acc = __builtin_amdgcn_mfma_f32_16x16x32_bf16(aL, bH, acc, 0, 0, 0);
  acc = __builtin_amdgcn_mfma_f32_16x16x32_bf16(aH, bL, acc, 0, 0, 0);
  acc = __builtin_amdgcn_mfma_f32_16x16x32_bf16(aH, bH, acc, 0, 0, 0);
  return acc;
}

// ---------------- split-MFMA GEMM: C[M,N] = act(A[M,K] @ W[N,K]^T + bias) ----------------
__global__ __launch_bounds__(256) void gemm_mfma_k(
    const float* __restrict__ A, int lda,
    const float* __restrict__ W, int ldw,
    const float* __restrict__ bias,
    float* __restrict__ C,
    int M, int N, int K, int op)
{
  __shared__ unsigned short AsH[64*32], AsL[64*32];
  __shared__ unsigned short WsH[64*32], WsL[64*32];
  const int tid = threadIdx.x;
  const int bm = blockIdx.y * 64, bn = blockIdx.x * 64;
  const int wave = tid >> 6, lane = tid & 63;
  const int wr = wave >> 1, wc = wave & 1;
  const int quad = lane >> 4, id = lane & 15;

  f32x4 acc[2][2] = {};
  const int iters = (K + 31) / 32;
  for (int kt = 0; kt < iters; ++kt){
    int k0 = kt * 32;
    stage2(A, lda, bm, M, k0, K, AsH, AsL, tid);
    stage2(W, ldw, bn, N, k0, K, WsH, WsL, tid);
    __syncthreads();
    short8 aH[2], aL[2], bH[2], bL[2];
    #pragma unroll
    for (int i = 0; i < 2; ++i){
      int off = (wr*32 + i*16 + id)*32 + quad*8;
      aH[i] = *(const short8*)&AsH[off];
      aL[i] = *(const short8*)&AsL[off];
    }
    #pragma unroll
    for (int j = 0; j < 2; ++j){
      int off = (wc*32 + j*16 + id)*32 + quad*8;
      bH[j] = *(const short8*)&WsH[off];
      bL[j] = *(const short8*)&WsL[off];
    }
    #pragma unroll
    for (int i = 0; i < 2; ++i)
      #pragma unroll
      for (int j = 0; j < 2; ++j)
        acc[i][j] = mfma3(aH[i], aL[i], bH[j], bL[j], acc[i][j]);
    __syncthreads();
  }
  #pragma unroll
  for (int i = 0; i < 2; ++i){
    int gr0 = bm + wr*32 + i*16 + quad*4;
    #pragma unroll
    for (int j = 0; j < 2; ++j){
      int gc = bn + wc*32 + j*16 + id;
      if (gc >= N) continue;
      float bv = bias ? bias[gc] : 0.f;
      #pragma unroll
      for (int r = 0; r < 4; ++r){
        int row = gr0 + r;
        if (row < M)
          C[(size_t)row*N + gc] = applyOp(acc[i][j][r] + bv, op);
      }
    }
  }
}

// ---------------- fused split-MFMA GRU: Out = relu(gru(Xin, Hid)) ----------------
__global__ __launch_bounds__(256) void gru_mfma_k(
    const float* __restrict__ Xin, const float* __restrict__ Hid,
    const float* __restrict__ wih, const float* __restrict__ whh,
    const float* __restrict__ bih, const float* __restrict__ bhh,
    float* __restrict__ Out, int M)
{
  __shared__ unsigned short AsH[64*32], AsL[64*32];
  __shared__ unsigned short WrH[64*32], WrL[64*32];
  __shared__ unsigned short WzH[64*32], WzL[64*32];
  __shared__ unsigned short WnH[64*32], WnL[64*32];
  const int tid = threadIdx.x;
  const int bm = blockIdx.y * 64, bn = blockIdx.x * 64;   // bn in [0,256)
  const int wave = tid >> 6, lane = tid & 63;
  const int wr = wave >> 1, wc = wave & 1;
  const int quad = lane >> 4, id = lane & 15;

  f32x4 accR[2][2] = {}, accZ[2][2] = {}, accI[2][2] = {}, accH[2][2] = {};

  for (int kt = 0; kt < 16; ++kt){
    const int ph = kt >> 3;                 // 0: Xin/wih, 1: Hid/whh
    const int ks = (kt & 7) * 32;
    const float* Asrc = ph ? Hid : Xin;
    const float* Wb   = ph ? whh : wih;
    stage2(Asrc,          256, bm, M,   ks, 256, AsH, AsL, tid);
    stage2(Wb,            256, bn, 256, ks, 256, WrH, WrL, tid);
    stage2(Wb + 256*256,  256, bn, 256, ks, 256, WzH, WzL, tid);
    stage2(Wb + 512*256,  256, bn, 256, ks, 256, WnH, WnL, tid);
    __syncthreads();
    short8 aH[2], aL[2];
    #pragma unroll
    for (int i = 0; i < 2; ++i){
      int off = (wr*32 + i*16 + id)*32 + quad*8;
      aH[i] = *(const short8*)&AsH[off];
      aL[i] = *(const short8*)&AsL[off];
    }
    #pragma unroll
    for (int j = 0; j < 2; ++j){
      const int boff = (wc*32 + j*16 + id)*32 + quad*8;
      short8 brH = *(const short8*)&WrH[boff], brL = *(const short8*)&WrL[boff];
      short8 bzH = *(const short8*)&WzH[boff], bzL = *(const short8*)&WzL[boff];
      short8 bnH = *(const short8*)&WnH[boff], bnL = *(const short8*)&WnL[boff];
      #pragma unroll
      for (int i = 0; i < 2; ++i){
        accR[i][j] = mfma3(aH[i], aL[i], brH, brL, accR[i][j]);
        accZ[i][j] = mfma3(aH[i], aL[i], bzH, bzL, accZ[i][j]);
        if (kt < 8) accI[i][j] = mfma3(aH[i], aL[i], bnH, bnL, accI[i][j]);
        else        accH[i][j] = mfma3(aH[i], aL[i], bnH, bnL, accH[i][j]);
      }
    }
    __syncthreads();
  }

  #pragma unroll
  for (int i = 0; i < 2; ++i){
    int gr0 = bm + wr*32 + i*16 + quad*4;
    #pragma unroll
    for (int j = 0; j < 2; ++j){
      int gc = bn + wc*32 + j*16 + id;
      float br_  = bih[gc]     + bhh[gc];
      float bz_  = bih[256+gc] + bhh[256+gc];
      float bn_i = bih[512+gc], bn_h = bhh[512+gc];
      #pragma unroll
      for (int r = 0; r < 4; ++r){
        int row = gr0 + r;
        if (row >= M) continue;
        float rg = sigf(accR[i][j][r] + br_);
        float zg = sigf(accZ[i][j][r] + bz_);
        float ng = tanhf(accI[i][j][r] + bn_i + rg*(accH[i][j][r] + bn_h));
        float hv = Hid[(size_t)row*256 + gc];
        float o = (1.f - zg)*ng + zg*hv;
        Out[(size_t)row*256 + gc] = o > 0.f ? o : 0.f;
      }
    }
  }
}

// ---------------- row dots: y1[m]=dot(X[m,:256],w1), y2 optional ----------------
__global__ __launch_bounds__(256) void rowdot2_k(const float* __restrict__ X,
    const float* __restrict__ w1, const float* __restrict__ w2,
    float* __restrict__ y1, float* __restrict__ y2, int M)
{
  int m = blockIdx.x*4 + (threadIdx.x >> 6);
  if (m >= M) return;
  int lane = threadIdx.x & 63;
  float p1 = 0.f, p2 = 0.f;
  for (int c = lane; c < 256; c += 64){
    float xv = X[(size_t)m*256 + c];
    p1 += xv * w1[c];
    if (w2) p2 += xv * w2[c];
  }
  for (int o = 32; o > 0; o >>= 1){
    p1 += __shfl_down(p1, o);
    if (w2) p2 += __shfl_down(p2, o);
  }
  if (lane == 0){ y1[m] = p1; if (w2) y2[m] = p2; }
}

// ================= CSR build (dst-sorted incoming-edge lists) =================
__global__ void hist_k(const int* __restrict__ dst, unsigned* __restrict__ deg, int E){
  int e = blockIdx.x*256 + threadIdx.x;
  if (e >= E) return;
  atomicAdd(&deg[dst[e]], 1u);
}

// inclusive block scan of deg -> incl, per-block totals -> bsum
__global__ __launch_bounds__(256) void scan1_k(const unsigned* __restrict__ deg,
    unsigned* __restrict__ incl, unsigned* __restrict__ bsum, int N)
{
  __shared__ unsigned sm[256];
  int t = threadIdx.x;
  int i = blockIdx.x*256 + t;
  unsigned v = (i < N) ? deg[i] : 0u;
  sm[t] = v; __syncthreads();
  for (int s = 1; s < 256; s <<= 1){
    unsigned u = (t >= s) ? sm[t - s] : 0u;
    __syncthreads();
    sm[t] += u;
    __syncthreads();
  }
  if (i < N) incl[i] = sm[t];
  if (t == 255) bsum[blockIdx.x] = sm[255];
}

// single-block exclusive scan over nb block sums (in place)
__global__ __launch_bounds__(256) void scan2_k(unsigned* __restrict__ bsum, int nb){
  __shared__ unsigned sm[256];
  __shared__ unsigned carry;
  int t = threadIdx.x;
  if (t == 0) carry = 0u;
  __syncthreads();
  for (int base = 0; base < nb; base += 256){
    int i = base + t;
    unsigned v = (i < nb) ? bsum[i] : 0u;
    sm[t] = v; __syncthreads();
    for (int s = 1; s < 256; s <<= 1){
      unsigned u = (t >= s) ? sm[t - s] : 0u;
      __syncthreads();
      sm[t] += u;
      __syncthreads();
    }
    unsigned total = sm[255];
    unsigned c = carry;
    if (i < nb) bsum[i] = c + sm[t] - v;
    __syncthreads();
    if (t == 0) carry = c + total;
    __syncthreads();
  }
}

// off[n] = exclusive scan; off[N] = E
__global__ void scan3_k(const unsigned* __restrict__ incl, const unsigned* __restrict__ deg,
    const unsigned* __restrict__ bsum, unsigned* __restrict__ off, int N, int E)
{
  int i = blockIdx.x*256 + threadIdx.x;
  if (i < N) off[i] = incl[i] - deg[i] + bsum[blockIdx.x];
  if (i == 0) off[N] = (unsigned)E;
}

__global__ void fill_k(const int* __restrict__ src, const int* __restrict__ dst,
    const unsigned* __restrict__ off, unsigned* __restrict__ cur,
    int* __restrict__ csr_src, int* __restrict__ csr_eid, int E)
{
  int e = blockIdx.x*256 + threadIdx.x;
  if (e >= E) return;
  int d = dst[e];
  unsigned p = off[d] + atomicAdd(&cur[d], 1u);
  csr_src[p] = src[e];
  csr_eid[p] = e;
}

// ---------------- GATEConv edge score, written in CSR order ----------------
__global__ __launch_bounds__(256) void gate_edge_score_csr_k(
    const float* __restrict__ Y, const float* __restrict__ g_lin1W,
    const float* __restrict__ att_l, const float* __restrict__ ea_in,
    const float* __restrict__ xr, const int* __restrict__ csr_src,
    const int* __restrict__ csr_eid, const int* __restrict__ dst,
    float* __restrict__ a_out, int E, int H)
{
  int p = blockIdx.x*4 + (threadIdx.x >> 6);
  if (p >= E) return;
  int lane = threadIdx.x & 63;
  int s = csr_src[p];
  int e = csr_eid[p];
  int d = dst[e];
  float eav = ea_in[e];
  float acc = 0.f;
  for (int c = lane; c < 256; c += 64){
    float yv = Y[(size_t)s*256 + c] + eav * g_lin1W[(size_t)c*(H+1) + H];
    acc += lreluf(yv) * att_l[c];
  }
  for (int o = 32; o > 0; o >>= 1) acc += __shfl_down(acc, o);
  if (lane == 0) a_out[p] = lreluf(acc + xr[d]);
}

// ---------------- per-node segment softmax over CSR (no atomics) ----------------
// mode 0: raw scores already in w[p] (CSR order); mode 1: a = lrelu(nd1[src]+nd2[n])
__global__ void node_softmax_k(const unsigned* __restrict__ off, const int* __restrict__ csr_src,
    const float* __restrict__ nd1, const float* __restrict__ nd2,
    float* __restrict__ w, int N, int mode)
{
  int n = blockIdx.x*256 + threadIdx.x;
  if (n >= N) return;
  unsigned p0 = off[n], p1 = off[n+1];
  float m = -INFINITY;
  if (mode){
    float d = nd2[n];
    for (unsigned p = p0; p < p1; ++p){
      float a = lreluf(nd1[csr_src[p]] + d);
      w[p] = a;
      m = fmaxf(m, a);
    }
  } else {
    for (unsigned p = p0; p < p1; ++p) m = fmaxf(m, w[p]);
  }
  float ssum = 0.f;
  for (unsigned p = p0; p < p1; ++p){
    float e = expf(w[p] - m);
    w[p] = e; ssum += e;
  }
  float inv = (ssum > 0.f) ? 1.f/ssum : 0.f;
  for (unsigned p = p0; p < p1; ++p) w[p] *= inv;
}

// ---------------- gather: h[n] = elu( sum_e w[e]*Z[src[e]] + bias ) ----------------
__global__ __launch_bounds__(256) void gather_h_k(const float* __restrict__ Z,
    const float* __restrict__ w, const unsigned* __restrict__ off,
    const int* __restrict__ csr_src, const float* __restrict__ bias,
    float* __restrict__ h, int N)
{
  int n = blockIdx.x*4 + (threadIdx.x >> 6);
  if (n >= N) return;
  int lane = threadIdx.x & 63;
  unsigned p0 = off[n], p1 = off[n+1];
  float4 acc = make_float4(0.f, 0.f, 0.f, 0.f);
  for (unsigned p = p0; p < p1; ++p){
    float wv = w[p];
    const float4 z = *(const float4*)&Z[(size_t)csr_src[p]*256 + lane*4];
    acc.x = fmaf(wv, z.x, acc.x);
    acc.y = fmaf(wv, z.y, acc.y);
    acc.z = fmaf(wv, z.z, acc.z);
    acc.w = fmaf(wv, z.w, acc.w);
  }
  const float4 b = *(const float4*)&bias[lane*4];
  float4 o;
  float v;
  v = acc.x + b.x; o.x = v > 0.f ? v : expf(v) - 1.f;
  v = acc.y + b.y; o.y = v > 0.f ? v : expf(v) - 1.f;
  v = acc.z + b.z; o.z = v > 0.f ? v : expf(v) - 1.f;
  v = acc.w + b.w; o.w = v > 0.f ? v : expf(v) - 1.f;
  *(float4*)&h[(size_t)n*256 + lane*4] = o;
}

// ---------------- pooling ----------------
__global__ void seg_bounds_k(const int* __restrict__ batch, unsigned* __restrict__ gs,
                             unsigned* __restrict__ ge, int N){
  int n = blockIdx.x*256 + threadIdx.x;
  if (n >= N) return;
  int g = batch[n];
  atomicMin(&gs[g], (unsigned)n);
  atomicMax(&ge[g], (unsigned)(n+1));
}
__global__ __launch_bounds__(256) void graph_pool_k(const float* __restrict__ x,
    const unsigned* __restrict__ gs, const unsigned* __restrict__ ge,
    float* __restrict__ outg)
{
  int g = blockIdx.x, t = threadIdx.x;
  unsigned s0 = gs[g], e0 = ge[g];
  float acc = 0.f;
  for (unsigned n = s0; n < e0; ++n) acc += x[(size_t)n*256 + t];
  outg[(size_t)g*256 + t] = acc > 0.f ? acc : 0.f;
}
__global__ void precompute_v_k(const float* __restrict__ W, const float* __restrict__ ad,
                               float* __restrict__ v){
  int i = threadIdx.x;
  float acc = 0.f;
  for (int j = 0; j < 256; ++j) acc += W[(size_t)j*256 + i] * ad[j];
  v[i] = acc;
}
// fused mol attention timestep
__global__ __launch_bounds__(256) void mol_pool_k(const float* __restrict__ outg,
    const float* __restrict__ v, const float* __restrict__ asrc,
    const float* __restrict__ xw, const unsigned* __restrict__ gs,
    const unsigned* __restrict__ geb, const float* __restrict__ bias,
    float* __restrict__ hg)
{
  __shared__ float red[256];
  int g = blockIdx.x, t = threadIdx.x;
  float tg = blkSum(outg[(size_t)g*256 + t] * v[t], red);
  unsigned s0 = gs[g], e0 = geb[g];
  float mx = -INFINITY;
  for (unsigned n = s0 + t; n < e0; n += 256) mx = fmaxf(mx, lreluf(asrc[n] + tg));
  mx = blkMax(mx, red);
  float sm = 0.f;
  for (unsigned n = s0 + t; n < e0; n += 256) sm += expf(lreluf(asrc[n] + tg) - mx);
  sm = blkSum(sm, red);
  float acc = 0.f;
  if (e0 > s0 && sm > 0.f){
    float inv = 1.f / sm;
    for (unsigned n = s0; n < e0; ++n){
      float w = expf(lreluf(asrc[n] + tg) - mx) * inv;
      acc = fmaf(w, xw[(size_t)n*256 + t], acc);
    }
  }
  float h = acc + bias[t];
  hg[(size_t)g*256 + t] = h > 0.f ? h : expf(h) - 1.f;
}

// ---------------- launcher ----------------
extern "C" void kernel_launch(void* const* d_in, const int* in_sizes, int n_in,
                              void* d_out, int out_size, void* d_ws, size_t ws_size,
                              hipStream_t stream)
{
  (void)n_in; (void)ws_size;
  const int H    = in_sizes[3];          // 256
  const int NIN  = in_sizes[2] / H;      // 300
  const int N    = in_sizes[0] / NIN;    // 100000
  const int E    = in_sizes[1];          // 400000
  const int NL   = in_sizes[16] / H;     // 3
  const int NHID = in_sizes[30];         // 512
  const int NOUT = in_sizes[32];         // 768
  const int G    = out_size / NOUT;      // 2048
  const int T    = 16;

  const float* x_in     = (const float*)d_in[0];
  const float* ea_in    = (const float*)d_in[1];
  const float* lin1_W   = (const float*)d_in[2];
  const float* lin1_b   = (const float*)d_in[3];
  const float* g_lin1W  = (const float*)d_in[4];
  const float* g_lin2W  = (const float*)d_in[5];
  const float* g_att_l  = (const float*)d_in[6];
  const float* g_att_r  = (const float*)d_in[7];
  const float* g_bias   = (const float*)d_in[8];
  const float* gru0_wih = (const float*)d_in[9];
  const float* gru0_whh = (const float*)d_in[10];
  const float* gru0_bih = (const float*)d_in[11];
  const float* gru0_bhh = (const float*)d_in[12];
  const float* atom_W   = (const float*)d_in[13];
  const float* atom_as  = (const float*)d_in[14];
  const float* atom_ad  = (const float*)d_in[15];
  const float* atom_b   = (const float*)d_in[16];
  const float* agru_wih = (const float*)d_in[17];
  const float* agru_whh = (const float*)d_in[18];
  const float* agru_bih = (const float*)d_in[19];
  const float* agru_bhh = (const float*)d_in[20];
  const float* mol_W    = (const float*)d_in[21];
  const float* mol_as   = (const float*)d_in[22];
  const float* mol_ad   = (const float*)d_in[23];
  const float* mol_b    = (const float*)d_in[24];
  const float* mgru_wih = (const float*)d_in[25];
  const float* mgru_whh = (const float*)d_in[26];
  const float* mgru_bih = (const float*)d_in[27];
  const float* mgru_bhh = (const float*)d_in[28];
  const float* lin2_W   = (const float*)d_in[29];
  const float* lin2_b   = (const float*)d_in[30];
  const float* fc1_W    = (const float*)d_in[31];
  const float* fc1_b    = (const float*)d_in[32];
  const int*  eidx      = (const int*)d_in[33];
  const int*  batch     = (const int*)d_in[34];
  const int*  srcI = eidx;
  const int*  dstI = eidx + E;

  char* wp = (char*)d_ws;
  auto alloc = [&](size_t bytes)->void*{
    void* p = (void*)wp;
    wp += (bytes + 255) & ~(size_t)255;
    return p;
  };
  float*    x     = (float*)alloc((size_t)N*H*4);
  float*    hb    = (float*)alloc((size_t)N*H*4);
  float*    tA    = (float*)alloc((size_t)N*H*4);
  float*    tB    = (float*)alloc((size_t)N*H*4);
  float*    ea    = (float*)alloc((size_t)E*4);       // CSR-ordered scores/weights
  float*    nd1   = (float*)alloc((size_t)N*4);
  float*    nd2   = (float*)alloc((size_t)N*4);
  float*    outg  = (float*)alloc((size_t)G*H*4);
  float*    outg2 = (float*)alloc((size_t)G*H*4);
  float*    hg    = (float*)alloc((size_t)G*H*4);
  unsigned* gsb   = (unsigned*)alloc((size_t)G*4);
  unsigned* geb   = (unsigned*)alloc((size_t)G*4);
  float*    vvec  = (float*)alloc((size_t)H*4);
  float*    o2    = (float*)alloc((size_t)G*NHID*4);
  // CSR structures
  const int nb = (N + 255) / 256;
  unsigned* deg     = (unsigned*)alloc((size_t)N*4);
  unsigned* cur     = (unsigned*)alloc((size_t)N*4);
  unsigned* incl    = (unsigned*)alloc((size_t)N*4);
  unsigned* off     = (unsigned*)alloc((size_t)(N+1)*4);
  unsigned* bsum    = (unsigned*)alloc((size_t)nb*4);
  int*      csr_src = (int*)alloc((size_t)E*4);
  int*      csr_eid = (int*)alloc((size_t)E*4);

  auto gemm = [&](const float* Ain, int lda, const float* W, int ldw, const float* bias,
                  float* Cout, int M_, int N_, int K_, int op){
    dim3 gr((N_ + 63)/64, (M_ + 63)/64);
    gemm_mfma_k<<<gr, dim3(256), 0, stream>>>(Ain, lda, W, ldw, bias, Cout, M_, N_, K_, op);
  };
  auto gru = [&](const float* xin, const float* hid, const float* wih, const float* whh,
                 const float* bih, const float* bhh, float* out, int M_){
    gru_mfma_k<<<dim3(4, (M_ + 63)/64), dim3(256), 0, stream>>>(xin, hid, wih, whh, bih, bhh, out, M_);
  };

  // ---- build CSR of incoming edges (reused by all 4 attention layers)
  hipMemsetAsync(deg, 0, (size_t)N*4, stream);
  hist_k<<<dim3((E+255)/256), dim3(256), 0, stream>>>(dstI, deg, E);
  scan1_k<<<dim3(nb), dim3(256), 0, stream>>>(deg, incl, bsum, N);
  scan2_k<<<dim3(1), dim3(256), 0, stream>>>(bsum, nb);
  scan3_k<<<dim3(nb), dim3(256), 0, stream>>>(incl, deg, bsum, off, N, E);
  hipMemsetAsync(cur, 0, (size_t)N*4, stream);
  fill_k<<<dim3((E+255)/256), dim3(256), 0, stream>>>(srcI, dstI, off, cur, csr_src, csr_eid, E);

  // ---- input projection (K=300, zero-padded in staging)
  gemm(x_in, NIN, lin1_W, NIN, lin1_b, x, N, H, NIN, OP_LRELU);

  // ---- GATEConv
  gemm(x, H, g_lin1W, H+1, nullptr, tA, N, H, H, OP_NONE);                     // Y
  rowdot2_k<<<dim3((N+3)/4), dim3(256), 0, stream>>>(x, g_att_r, (const float*)nullptr,
                                                     nd1, (float*)nullptr, N);
  gate_edge_score_csr_k<<<dim3((E+3)/4), dim3(256), 0, stream>>>(tA, g_lin1W, g_att_l,
                                                                 ea_in, nd1, csr_src, csr_eid,
                                                                 dstI, ea, E, H);
  gemm(x, H, g_lin2W, H, nullptr, tA, N, H, H, OP_NONE);                       // Z
  node_softmax_k<<<dim3(nb), dim3(256), 0, stream>>>(off, csr_src, nullptr, nullptr, ea, N, 0);
  gather_h_k<<<dim3((N+3)/4), dim3(256), 0, stream>>>(tA, ea, off, csr_src, g_bias, hb, N);
  gru(hb, x, gru0_wih, gru0_whh, gru0_bih, gru0_bhh, tB, N);
  { float* t = x; x = tB; tB = t; }

  // ---- atom GATConv layers
  for (int l = 0; l < NL; ++l){
    gemm(x, H, atom_W + (size_t)l*H*H, H, nullptr, tA, N, H, H, OP_NONE);      // xw
    rowdot2_k<<<dim3((N+3)/4), dim3(256), 0, stream>>>(tA, atom_as + (size_t)l*H,
                                                       atom_ad + (size_t)l*H, nd1, nd2, N);
    node_softmax_k<<<dim3(nb), dim3(256), 0, stream>>>(off, csr_src, nd1, nd2, ea, N, 1);
    gather_h_k<<<dim3((N+3)/4), dim3(256), 0, stream>>>(tA, ea, off, csr_src,
                                                        atom_b + (size_t)l*H, hb, N);
    gru(hb, x, agru_wih + (size_t)l*3*H*H, agru_whh + (size_t)l*3*H*H,
        agru_bih + (size_t)l*3*H, agru_bhh + (size_t)l*3*H, tB, N);
    { float* t = x; x = tB; tB = t; }
  }

  // ---- attentive pooling
  hipMemsetAsync(gsb, 0xFF, (size_t)G*4, stream);
  hipMemsetAsync(geb, 0x00, (size_t)G*4, stream);
  seg_bounds_k<<<dim3((N+255)/256), dim3(256), 0, stream>>>(batch, gsb, geb, N);
  graph_pool_k<<<dim3(G), dim3(256), 0, stream>>>(x, gsb, geb, outg);
  gemm(x, H, mol_W, H, nullptr, hb, N, H, H, OP_NONE);                         // xw (persists)
  rowdot2_k<<<dim3((N+3)/4), dim3(256), 0, stream>>>(hb, mol_as, (const float*)nullptr,
                                                     nd1, (float*)nullptr, N);
  precompute_v_k<<<dim3(1), dim3(256), 0, stream>>>(mol_W, mol_ad, vvec);
  float* og  = outg;
  float* og2 = outg2;
  for (int t = 0; t < T; ++t){
    mol_pool_k<<<dim3(G), dim3(256), 0, stream>>>(og, vvec, nd1, hb, gsb, geb, mol_b, hg);
    gru(hg, og, mgru_wih, mgru_whh, mgru_bih, mgru_bhh, og2, G);
    { float* tt = og; og = og2; og2 = tt; }
  }

  // ---- head
  gemm(og, H, lin2_W, H, lin2_b, o2, G, NHID, H, OP_RELU);
  gemm(o2, NHID, fc1_W, NHID, fc1_b, (float*)d_out, G, NOUT, NHID, OP_NONE);
}